// Round 3
// baseline (252.858 us; speedup 1.0000x reference)
//
#include <hip/hip_runtime.h>
#include <hip/hip_bf16.h>
#include <stdint.h>

#define VOCAB 50257
#define WD 300
#define KP1 320              // word dim padded to mult of 32
#define MP 50432             // vocab rows padded: 394*128

using bf16 = __hip_bfloat16;
typedef __attribute__((ext_vector_type(4))) float f32x4;
typedef __attribute__((ext_vector_type(8))) short bf16x8;

// async global->LDS, 16B per lane; LDS dest = wave-uniform base + lane*16
__device__ __forceinline__ void async_load16(const void* g, void* l) {
    __builtin_amdgcn_global_load_lds(
        (const __attribute__((address_space(1))) uint32_t*)(uintptr_t)g,
        (__attribute__((address_space(3))) uint32_t*)l, 16, 0, 0);
}

// ---------- prep: w1t = W1^T bf16 [256x320]; w2t = W2^T bf16 [256x512];
//                  w2b = W2 cast bf16 [512x256]; b4 = b2@(A+B)+b2; zbuf zeros
__global__ void prep_w(const float* __restrict__ W1, const float* __restrict__ W2,
                       const float* __restrict__ b2,
                       bf16* __restrict__ w1t, bf16* __restrict__ w2t,
                       bf16* __restrict__ w2b, float* __restrict__ b4,
                       float* __restrict__ zbuf) {
    if (blockIdx.x == 1344) {           // bias block: b4 = b2@(A+B) + b2
        __shared__ float b2s[256];
        int n = threadIdx.x;
        b2s[n] = b2[n];
        zbuf[n] = 0.0f;
        __syncthreads();
        float acc = b2s[n];
        #pragma unroll 8
        for (int k = 0; k < 256; ++k)
            acc += b2s[k] * (W2[k * 256 + n] + W2[(k + 256) * 256 + n]);
        b4[n] = acc;
        return;
    }
    int idx = blockIdx.x * 256 + threadIdx.x;
    if (idx < 256 * KP1) {                              // w1t = W1^T (zero-pad)
        int n = idx / KP1;
        int k = idx - n * KP1;
        w1t[idx] = __float2bfloat16(k < WD ? W1[k * 256 + n] : 0.0f);
    } else if (idx < 256 * KP1 + 131072) {              // w2t = W2^T
        int j = idx - 256 * KP1;
        int n = j >> 9, k = j & 511;
        w2t[j] = __float2bfloat16(W2[k * 256 + n]);
    } else {                                            // w2b = cast(W2)
        int j = idx - 256 * KP1 - 131072;
        w2b[j] = __float2bfloat16(W2[j]);
    }
}

// ---------- unified 128-row x 256-col tile (8 waves: 2 rg x 4 cgr) -----------
// AMODE 0: A bf16, row stride As elems; 3-stage PIPE (verified R8/R10/R12)
// AMODE 1: A row r = concat4(proj[ids4[m0+r]]), K = 1024; 3-stage PIPE
// AMODE 2: A fp32 rows stride WD (emb, clamped); 2-stage PIPE w/ raw barriers
template <int AMODE, bool OUT_F32>
__device__ __forceinline__ void tile_gemm(
    char* smem, const void* Av, const int* ids,
    const bf16* BT, int Bstr, const float* bias,
    void* C, int Cs, int coff, int K, int As, int m0,
    const float* zbuf)
{
    constexpr int ASZ = (AMODE == 2) ? 16384 : 8192;
    constexpr int BSZ = 16384, STAGE = ASZ + BSZ;

    const int t = threadIdx.x, w = t >> 6, lane = t & 63;
    const int rg = w >> 2, cgr = w & 3, mi = lane & 15, q = lane >> 4;
    const bf16* Ab = (const bf16*)Av;

    int4 idq = {0, 0, 0, 0};
    if constexpr (AMODE == 1) idq = ((const int4*)ids)[m0 + (t >> 2)];

    auto stage = [&](int ke, int buf) {
        char* Asm = smem + buf * STAGE;
        char* Bsm = Asm + ASZ;
        if constexpr (AMODE == 2) {
            const float* A32 = (const float*)Av;
            #pragma unroll
            for (int i = 0; i < 2; ++i) {
                int s = i * 512 + t;
                int row = s >> 3;
                int kcd = (s & 7) ^ (row & 7);
                int k = ke + kcd * 4;
                int grow = m0 + row; if (grow >= VOCAB) grow = VOCAB - 1;
                const float* g = (k <= 296) ? (A32 + (size_t)grow * WD + k) : zbuf;
                async_load16(g, Asm + i * 8192 + w * 1024);
            }
        } else {
            int row = t >> 2;
            int kcd = (t & 3) ^ ((row >> 2) & 3);
            const bf16* g;
            if constexpr (AMODE == 1) {
                int sel = ke >> 8;
                int id = (sel & 2) ? ((sel & 1) ? idq.w : idq.z)
                                   : ((sel & 1) ? idq.y : idq.x);
                g = Ab + (size_t)id * 256 + (ke & 255) + kcd * 8;
            } else {
                g = Ab + (size_t)(m0 + row) * As + ke + kcd * 8;
            }
            async_load16(g, Asm + w * 1024);
        }
        #pragma unroll
        for (int i = 0; i < 2; ++i) {
            int s = i * 512 + t;
            int col = s >> 2;
            int kcd = (s & 3) ^ ((col >> 2) & 3);
            async_load16(BT + (size_t)col * Bstr + ke + kcd * 8,
                         Bsm + i * 8192 + w * 1024);
        }
    };

    f32x4 acc[4][4] = {};

    auto compute = [&](int buf) {
        const char* Asm = smem + buf * STAGE;
        const bf16* Bs16 = (const bf16*)(Asm + ASZ);
        bf16x8 af[4], bfr[4];
        if constexpr (AMODE == 2) {
            const float* As32 = (const float*)Asm;
            #pragma unroll
            for (int r = 0; r < 4; ++r) {
                int row = rg * 64 + r * 16 + mi;
                int sl = row * 8 + ((2 * q) ^ (row & 7));
                f32x4 lo = *(const f32x4*)(As32 + sl * 4);
                f32x4 hi = *(const f32x4*)(As32 + (sl ^ 1) * 4);
                union { bf16x8 v; bf16 hh[8]; } u;
                #pragma unroll
                for (int j = 0; j < 4; ++j) u.hh[j] = __float2bfloat16(lo[j]);
                #pragma unroll
                for (int j = 0; j < 4; ++j) u.hh[4 + j] = __float2bfloat16(hi[j]);
                af[r] = u.v;
            }
        } else {
            const bf16* As16 = (const bf16*)Asm;
            #pragma unroll
            for (int r = 0; r < 4; ++r) {
                int row = rg * 64 + r * 16 + mi;
                int slot = row * 4 + (q ^ ((row >> 2) & 3));
                af[r] = *(const bf16x8*)(As16 + slot * 8);
            }
        }
        #pragma unroll
        for (int c = 0; c < 4; ++c) {
            int col = cgr * 64 + c * 16 + mi;
            int slot = col * 4 + (q ^ ((col >> 2) & 3));
            bfr[c] = *(const bf16x8*)(Bs16 + slot * 8);
        }
        #pragma unroll
        for (int r = 0; r < 4; ++r)
            #pragma unroll
            for (int c = 0; c < 4; ++c)
                acc[r][c] = __builtin_amdgcn_mfma_f32_16x16x32_bf16(af[r], bfr[c], acc[r][c], 0, 0, 0);
    };

    const int S = K >> 5;
    if constexpr (AMODE == 2) {
        // 2-stage PIPE with raw barriers (no compiler vmcnt(0) drain)
        stage(0, 0);
        for (int k0 = 0; k0 < S; ++k0) {
            if (k0 + 1 < S) {
                stage((k0 + 1) * 32, (k0 + 1) & 1);
                asm volatile("s_waitcnt vmcnt(4)\n\ts_barrier" ::: "memory");
            } else {
                asm volatile("s_waitcnt vmcnt(0)\n\ts_barrier" ::: "memory");
            }
            compute(k0 & 1);
            asm volatile("s_waitcnt lgkmcnt(0)\n\ts_barrier" ::: "memory");
        }
    } else {
        stage(0, 0);
        if (S > 1) stage(32, 1);
        for (int k0 = 0; k0 < S; ++k0) {
            if (k0 + 1 < S)
                asm volatile("s_waitcnt vmcnt(3)\n\ts_barrier" ::: "memory");
            else
                asm volatile("s_waitcnt vmcnt(0)\n\ts_barrier" ::: "memory");
            if (k0 + 2 < S) stage((k0 + 2) * 32, (k0 + 2) % 3);
            compute(k0 % 3);
        }
    }

    // epilogue: C/D layout col = lane&15, row = (lane>>4)*4 + i
    #pragma unroll
    for (int r = 0; r < 4; ++r) {
        int rowb = m0 + rg * 64 + r * 16 + q * 4;
        #pragma unroll
        for (int c = 0; c < 4; ++c) {
            int col = cgr * 64 + c * 16 + mi;
            float bv = bias[col];
            #pragma unroll
            for (int i = 0; i < 4; ++i) {
                float v = acc[r][c][i] + bv;
                size_t o = (size_t)(rowb + i) * Cs + coff + col;
                if (OUT_F32) ((float*)C)[o] = v;
                else         ((bf16*)C)[o] = __float2bfloat16(v);
            }
        }
    }
}

// ---------- D2: W4T (blocks 0..7) || proj (blocks 8..401) --------------------
__global__ __launch_bounds__(512)
void combo(const float* __restrict__ emb, const bf16* __restrict__ w1t,
           const float* __restrict__ b1, const bf16* __restrict__ w2t,
           const bf16* __restrict__ w2b, bf16* __restrict__ w4t,
           bf16* __restrict__ proj, const float* __restrict__ zbuf) {
    __shared__ char smem[73728];
    int blk = blockIdx.x;
    if (blk < 8) {
        int j = blk >> 1, s = blk & 1;
        tile_gemm<0, false>(smem, w2t + 256 * (j >> 1), nullptr,
                            w2b + 65536 * (j & 1), 256, zbuf,
                            w4t, 1024, 256 * j, 256, 512, s * 128, nullptr);
    } else {
        tile_gemm<2, false>(smem, emb, nullptr, w1t, KP1, b1,
                            proj, 256, 0, KP1, WD, (blk - 8) * 128, zbuf);
    }
}

// ---------- D3: main — h = concat4(proj[ids4]) @ W4 + b4 ---------------------
__global__ __launch_bounds__(512)
void mainK(const bf16* __restrict__ proj, const int* __restrict__ ids,
           const bf16* __restrict__ w4t, const float* __restrict__ b4,
           bf16* __restrict__ h) {
    __shared__ char smem[73728];
    tile_gemm<1, false>(smem, proj, ids, w4t, 1024, b4,
                        h, 256, 0, 1024, 256, blockIdx.x * 128, nullptr);
}

// ---------- D4..D7: tailW — barrier-FREE tree level-pair --------------------
// out[m][n] = sum_k A[m][k]*W4[k][n] + b4[n], A[m] = 1024 contiguous bf16
// (concat4 of 4 consecutive child rows). Block = 256 out-rows x 64 cols;
// grid = (rows/256) rowtiles x 4 colgroups. B slice (64 cols x 1024 k =
// 128 KB) staged in LDS ONCE (single barrier). Then 8 independent waves:
// wave w owns rows m0+w*32..+31, all 64 cols; A frags loaded DIRECTLY
// global->VGPR per lane (no LDS, no barriers) -> no per-round barrier
// latency (the 0.7-0.9us/round cost that dominated treeK/tailC).
template <bool OUT_F32>
__global__ __launch_bounds__(512)
void tailW(const bf16* __restrict__ in, const bf16* __restrict__ BT,
           const float* __restrict__ bias, void* __restrict__ out) {
    __shared__ char smem[131072];          // B slice only

    const int t = threadIdx.x, w = t >> 6, lane = t & 63;
    const int mi = lane & 15, q = lane >> 4;
    const int rt = blockIdx.x >> 2, cg = blockIdx.x & 3;
    const int m0 = rt * 256;
    const int c0 = cg * 64;

    // ---- B stage: 64 cols x 1024 k, once (16 loads/thread) ----
    // LDS byte = kc*4096 + col*64 + slot*16, slot = g ^ ((col>>2)&3)
    #pragma unroll
    for (int i = 0; i < 16; ++i) {
        int s = i * 512 + t;
        int kc = s >> 8;               // 0..31  (32-k chunk)
        int col = (s >> 2) & 63;
        int slot = s & 3;
        int g = slot ^ ((col >> 2) & 3);
        async_load16(BT + (size_t)(c0 + col) * 1024 + kc * 32 + g * 8,
                     smem + i * 8192 + w * 1024);
    }
    asm volatile("s_waitcnt vmcnt(0)\n\ts_barrier" ::: "memory");

    const bf16* Bs = (const bf16*)smem;
    const bf16* Arow0 = in + (size_t)(m0 + w * 32 + mi) * 1024 + q * 8;
    const bf16* Arow1 = Arow0 + (size_t)16 * 1024;

    f32x4 acc[2][4] = {};

    #pragma unroll 4
    for (int ks = 0; ks < 32; ++ks) {
        // A frags: lane (mi,q) reads 8 contiguous bf16 of row (w*32+f*16+mi)
        bf16x8 a0 = *(const bf16x8*)(Arow0 + ks * 32);
        bf16x8 a1 = *(const bf16x8*)(Arow1 + ks * 32);
        #pragma unroll
        for (int c = 0; c < 4; ++c) {
            int col = c * 16 + mi;
            int slot = q ^ ((col >> 2) & 3);
            bf16x8 bfr = *(const bf16x8*)(Bs + ks * 2048 + col * 32 + slot * 8);
            acc[0][c] = __builtin_amdgcn_mfma_f32_16x16x32_bf16(a0, bfr, acc[0][c], 0, 0, 0);
            acc[1][c] = __builtin_amdgcn_mfma_f32_16x16x32_bf16(a1, bfr, acc[1][c], 0, 0, 0);
        }
    }

    // epilogue: plain stores; col = lane&15, row = (lane>>4)*4 + i
    #pragma unroll
    for (int f = 0; f < 2; ++f) {
        int rowb = m0 + w * 32 + f * 16 + q * 4;
        #pragma unroll
        for (int c = 0; c < 4; ++c) {
            int col = c0 + c * 16 + mi;
            float bv = bias[col];
            #pragma unroll
            for (int i = 0; i < 4; ++i) {
                float v = acc[f][c][i] + bv;
                size_t o = (size_t)(rowb + i) * 256 + col;
                if (OUT_F32) ((float*)out)[o] = v;
                else         ((bf16*)out)[o] = __float2bfloat16(v);
            }
        }
    }
}

extern "C" void kernel_launch(void* const* d_in, const int* in_sizes, int n_in,
                              void* d_out, int out_size, void* d_ws, size_t ws_size,
                              hipStream_t stream) {
    const int*   ids = (const int*)d_in[0];
    const float* emb = (const float*)d_in[1];
    const float* W1  = (const float*)d_in[2];
    const float* b1  = (const float*)d_in[3];
    const float* W2  = (const float*)d_in[4];
    const float* b2  = (const float*)d_in[5];
    (void)in_sizes; (void)n_in; (void)out_size; (void)ws_size;

    char* ws = (char*)d_ws;
    size_t off = 0;
    float* zbuf = (float*)(ws + off); off += 1024;
    float* b4   = (float*)(ws + off); off += 1024;
    bf16* w1t = (bf16*)(ws + off); off += (size_t)256 * KP1 * 2;     // 160 KB
    bf16* w2t = (bf16*)(ws + off); off += (size_t)256 * 512 * 2;     // 256 KB
    bf16* w2b = (bf16*)(ws + off); off += (size_t)512 * 256 * 2;     // 256 KB
    bf16* w4t = (bf16*)(ws + off); off += (size_t)256 * 1024 * 2;    // 512 KB
    bf16* proj = (bf16*)(ws + off); off += (size_t)MP * 256 * 2;     // 25.8 MB
    bf16* h  = (bf16*)(ws + off); off += (size_t)65536 * 256 * 2;    // 33.5 MB
    (void)off;

    // bf16 tail intermediates alias proj (dead after mainK): 11 MB total
    bf16* t1 = (bf16*)proj;                 // [16384][256] levels 3-4
    bf16* t2 = t1 + (size_t)16384 * 256;    // [ 4096][256] levels 5-6
    bf16* t3 = t2 + (size_t)4096 * 256;     // [ 1024][256] levels 7-8

    // D1: weight casts/transposes + b4 + zeros
    prep_w<<<1345, 256, 0, stream>>>(W1, W2, b2, w1t, w2t, w2b, b4, zbuf);

    // D2: W4T (blocks 0..7) || proj (blocks 8..401, 2-stage PIPE raw barriers)
    combo<<<402, 512, 0, stream>>>(emb, w1t, b1, w2t, w2b, w4t, proj, zbuf);

    // D3: main — leaves + levels 0-1 fused (PIPE)
    mainK<<<512, 512, 0, stream>>>(proj, ids, w4t, b4, h);

    // D4..D7: tree tail, barrier-free waves (B-once in LDS, A direct to reg)
    tailW<false><<<256, 512, 0, stream>>>(h,  w4t, b4, t1);   // 16384 out rows
    tailW<false><<< 64, 512, 0, stream>>>(t1, w4t, b4, t2);   //  4096 out rows
    tailW<false><<< 16, 512, 0, stream>>>(t2, w4t, b4, t3);   //  1024 out rows
    tailW<true ><<<  4, 512, 0, stream>>>(t3, w4t, b4, d_out); //  256 roots
}

// Round 4
// 237.404 us; speedup vs baseline: 1.0651x; 1.0651x over previous
//
#include <hip/hip_runtime.h>
#include <hip/hip_bf16.h>
#include <stdint.h>

#define VOCAB 50257
#define WD 300
#define KP1 320              // word dim padded to mult of 32
#define MP 50432             // vocab rows padded: 394*128

using bf16 = __hip_bfloat16;
typedef __attribute__((ext_vector_type(4))) float f32x4;
typedef __attribute__((ext_vector_type(8))) short bf16x8;

// async global->LDS, 16B per lane; LDS dest = wave-uniform base + lane*16
__device__ __forceinline__ void async_load16(const void* g, void* l) {
    __builtin_amdgcn_global_load_lds(
        (const __attribute__((address_space(1))) uint32_t*)(uintptr_t)g,
        (__attribute__((address_space(3))) uint32_t*)l, 16, 0, 0);
}

// ---------- prep: w1t = W1^T bf16 [256x320]; w2t = W2^T bf16 [256x512];
//                  w2b = W2 cast bf16 [512x256]; b4 = b2@(A+B)+b2; zbuf zeros
__global__ void prep_w(const float* __restrict__ W1, const float* __restrict__ W2,
                       const float* __restrict__ b2,
                       bf16* __restrict__ w1t, bf16* __restrict__ w2t,
                       bf16* __restrict__ w2b, float* __restrict__ b4,
                       float* __restrict__ zbuf) {
    if (blockIdx.x == 1344) {           // bias block: b4 = b2@(A+B) + b2
        __shared__ float b2s[256];
        int n = threadIdx.x;
        b2s[n] = b2[n];
        zbuf[n] = 0.0f;
        __syncthreads();
        float acc = b2s[n];
        #pragma unroll 8
        for (int k = 0; k < 256; ++k)
            acc += b2s[k] * (W2[k * 256 + n] + W2[(k + 256) * 256 + n]);
        b4[n] = acc;
        return;
    }
    int idx = blockIdx.x * 256 + threadIdx.x;
    if (idx < 256 * KP1) {                              // w1t = W1^T (zero-pad)
        int n = idx / KP1;
        int k = idx - n * KP1;
        w1t[idx] = __float2bfloat16(k < WD ? W1[k * 256 + n] : 0.0f);
    } else if (idx < 256 * KP1 + 131072) {              // w2t = W2^T
        int j = idx - 256 * KP1;
        int n = j >> 9, k = j & 511;
        w2t[j] = __float2bfloat16(W2[k * 256 + n]);
    } else {                                            // w2b = cast(W2)
        int j = idx - 256 * KP1 - 131072;
        w2b[j] = __float2bfloat16(W2[j]);
    }
}

// ---------- unified 128-row x 256-col tile (8 waves: 2 rg x 4 cgr) -----------
// AMODE 0: A bf16, row stride As elems; 3-stage PIPE (verified R8/R10/R12)
// AMODE 1: A row r = concat4(proj[ids4[m0+r]]), K = 1024; 3-stage PIPE
// AMODE 2: A fp32 rows stride WD (emb, clamped); 2-stage PIPE w/ raw barriers
template <int AMODE, bool OUT_F32>
__device__ __forceinline__ void tile_gemm(
    char* smem, const void* Av, const int* ids,
    const bf16* BT, int Bstr, const float* bias,
    void* C, int Cs, int coff, int K, int As, int m0,
    const float* zbuf)
{
    constexpr int ASZ = (AMODE == 2) ? 16384 : 8192;
    constexpr int BSZ = 16384, STAGE = ASZ + BSZ;

    const int t = threadIdx.x, w = t >> 6, lane = t & 63;
    const int rg = w >> 2, cgr = w & 3, mi = lane & 15, q = lane >> 4;
    const bf16* Ab = (const bf16*)Av;

    int4 idq = {0, 0, 0, 0};
    if constexpr (AMODE == 1) idq = ((const int4*)ids)[m0 + (t >> 2)];

    auto stage = [&](int ke, int buf) {
        char* Asm = smem + buf * STAGE;
        char* Bsm = Asm + ASZ;
        if constexpr (AMODE == 2) {
            const float* A32 = (const float*)Av;
            #pragma unroll
            for (int i = 0; i < 2; ++i) {
                int s = i * 512 + t;
                int row = s >> 3;
                int kcd = (s & 7) ^ (row & 7);
                int k = ke + kcd * 4;
                int grow = m0 + row; if (grow >= VOCAB) grow = VOCAB - 1;
                const float* g = (k <= 296) ? (A32 + (size_t)grow * WD + k) : zbuf;
                async_load16(g, Asm + i * 8192 + w * 1024);
            }
        } else {
            int row = t >> 2;
            int kcd = (t & 3) ^ ((row >> 2) & 3);
            const bf16* g;
            if constexpr (AMODE == 1) {
                int sel = ke >> 8;
                int id = (sel & 2) ? ((sel & 1) ? idq.w : idq.z)
                                   : ((sel & 1) ? idq.y : idq.x);
                g = Ab + (size_t)id * 256 + (ke & 255) + kcd * 8;
            } else {
                g = Ab + (size_t)(m0 + row) * As + ke + kcd * 8;
            }
            async_load16(g, Asm + w * 1024);
        }
        #pragma unroll
        for (int i = 0; i < 2; ++i) {
            int s = i * 512 + t;
            int col = s >> 2;
            int kcd = (s & 3) ^ ((col >> 2) & 3);
            async_load16(BT + (size_t)col * Bstr + ke + kcd * 8,
                         Bsm + i * 8192 + w * 1024);
        }
    };

    f32x4 acc[4][4] = {};

    auto compute = [&](int buf) {
        const char* Asm = smem + buf * STAGE;
        const bf16* Bs16 = (const bf16*)(Asm + ASZ);
        bf16x8 af[4], bfr[4];
        if constexpr (AMODE == 2) {
            const float* As32 = (const float*)Asm;
            #pragma unroll
            for (int r = 0; r < 4; ++r) {
                int row = rg * 64 + r * 16 + mi;
                int sl = row * 8 + ((2 * q) ^ (row & 7));
                f32x4 lo = *(const f32x4*)(As32 + sl * 4);
                f32x4 hi = *(const f32x4*)(As32 + (sl ^ 1) * 4);
                union { bf16x8 v; bf16 hh[8]; } u;
                #pragma unroll
                for (int j = 0; j < 4; ++j) u.hh[j] = __float2bfloat16(lo[j]);
                #pragma unroll
                for (int j = 0; j < 4; ++j) u.hh[4 + j] = __float2bfloat16(hi[j]);
                af[r] = u.v;
            }
        } else {
            const bf16* As16 = (const bf16*)Asm;
            #pragma unroll
            for (int r = 0; r < 4; ++r) {
                int row = rg * 64 + r * 16 + mi;
                int slot = row * 4 + (q ^ ((row >> 2) & 3));
                af[r] = *(const bf16x8*)(As16 + slot * 8);
            }
        }
        #pragma unroll
        for (int c = 0; c < 4; ++c) {
            int col = cgr * 64 + c * 16 + mi;
            int slot = col * 4 + (q ^ ((col >> 2) & 3));
            bfr[c] = *(const bf16x8*)(Bs16 + slot * 8);
        }
        #pragma unroll
        for (int r = 0; r < 4; ++r)
            #pragma unroll
            for (int c = 0; c < 4; ++c)
                acc[r][c] = __builtin_amdgcn_mfma_f32_16x16x32_bf16(af[r], bfr[c], acc[r][c], 0, 0, 0);
    };

    const int S = K >> 5;
    if constexpr (AMODE == 2) {
        // 2-stage PIPE with raw barriers (no compiler vmcnt(0) drain)
        stage(0, 0);
        for (int k0 = 0; k0 < S; ++k0) {
            if (k0 + 1 < S) {
                stage((k0 + 1) * 32, (k0 + 1) & 1);
                asm volatile("s_waitcnt vmcnt(4)\n\ts_barrier" ::: "memory");
            } else {
                asm volatile("s_waitcnt vmcnt(0)\n\ts_barrier" ::: "memory");
            }
            compute(k0 & 1);
            asm volatile("s_waitcnt lgkmcnt(0)\n\ts_barrier" ::: "memory");
        }
    } else {
        stage(0, 0);
        if (S > 1) stage(32, 1);
        for (int k0 = 0; k0 < S; ++k0) {
            if (k0 + 1 < S)
                asm volatile("s_waitcnt vmcnt(3)\n\ts_barrier" ::: "memory");
            else
                asm volatile("s_waitcnt vmcnt(0)\n\ts_barrier" ::: "memory");
            if (k0 + 2 < S) stage((k0 + 2) * 32, (k0 + 2) % 3);
            compute(k0 % 3);
        }
    }

    // epilogue: C/D layout col = lane&15, row = (lane>>4)*4 + i
    #pragma unroll
    for (int r = 0; r < 4; ++r) {
        int rowb = m0 + rg * 64 + r * 16 + q * 4;
        #pragma unroll
        for (int c = 0; c < 4; ++c) {
            int col = cgr * 64 + c * 16 + mi;
            float bv = bias[col];
            #pragma unroll
            for (int i = 0; i < 4; ++i) {
                float v = acc[r][c][i] + bv;
                size_t o = (size_t)(rowb + i) * Cs + coff + col;
                if (OUT_F32) ((float*)C)[o] = v;
                else         ((bf16*)C)[o] = __float2bfloat16(v);
            }
        }
    }
}

// ---------- D2: W4T (blocks 0..7) || proj (blocks 8..401) --------------------
__global__ __launch_bounds__(512)
void combo(const float* __restrict__ emb, const bf16* __restrict__ w1t,
           const float* __restrict__ b1, const bf16* __restrict__ w2t,
           const bf16* __restrict__ w2b, bf16* __restrict__ w4t,
           bf16* __restrict__ proj, const float* __restrict__ zbuf) {
    __shared__ char smem[73728];
    int blk = blockIdx.x;
    if (blk < 8) {
        int j = blk >> 1, s = blk & 1;
        tile_gemm<0, false>(smem, w2t + 256 * (j >> 1), nullptr,
                            w2b + 65536 * (j & 1), 256, zbuf,
                            w4t, 1024, 256 * j, 256, 512, s * 128, nullptr);
    } else {
        tile_gemm<2, false>(smem, emb, nullptr, w1t, KP1, b1,
                            proj, 256, 0, KP1, WD, (blk - 8) * 128, zbuf);
    }
}

// ---------- D3: main — h = concat4(proj[ids4]) @ W4 + b4 ---------------------
__global__ __launch_bounds__(512)
void mainK(const bf16* __restrict__ proj, const int* __restrict__ ids,
           const bf16* __restrict__ w4t, const float* __restrict__ b4,
           bf16* __restrict__ h) {
    __shared__ char smem[73728];
    tile_gemm<1, false>(smem, proj, ids, w4t, 1024, b4,
                        h, 256, 0, 1024, 256, blockIdx.x * 128, nullptr);
}

// ---------- D4: treeK — levels 2-9 block-local (128 blocks) ------------------
// Phase A: verified 3-stage PIPE tile (unchanged from R0 baseline, 32 rounds).
// Phases B/C/D: B-fragments loaded DIRECTLY global->VGPR from w4t (L2-warm;
// per-lane 16B = exactly the MFMA B-frag: col*1024 + ks*32 + q*8). No LDS
// staging, no per-round barriers -> 48 latency-bound rounds replaced by 3
// __syncthreads. A-fragments read from LDS-resident Ht/Ht2/Ht3 with the
// R0-verified index formulas (r2=4m+(ks>>3), kc=(ks&7)*4+q, XOR swizzles).
__global__ __launch_bounds__(512)
void treeK(const bf16* __restrict__ h, const bf16* __restrict__ w4t,
           const float* __restrict__ b4, float* __restrict__ out) {
    constexpr int ASZ = 8192, BSZ = 16384, STAGE = ASZ + BSZ;
    __shared__ char smem[3 * STAGE];   // 72 KB (phase A pipe)
    __shared__ bf16 Ht[128 * 256];     // 64 KB
    __shared__ bf16 Ht2[32 * 256];     // 16 KB
    __shared__ bf16 Ht3[8 * 256];      // 4 KB   (total 156 KB)

    const int t = threadIdx.x, w = t >> 6, lane = t & 63;
    const int rg = w >> 2, cgr = w & 3, mi = lane & 15, q = lane >> 4;
    const int b = blockIdx.x;
    const int m0 = b * 128;

    // ---- phase A: t1 tile [128 x 256] (verified PIPE) -> Ht ----
    {
        auto stageA = [&](int ke, int buf) {
            char* Asm = smem + buf * STAGE;
            char* Bsm = Asm + ASZ;
            int row = t >> 2;
            int kcd = (t & 3) ^ ((row >> 2) & 3);
            async_load16(h + (size_t)(m0 + row) * 1024 + ke + kcd * 8, Asm + w * 1024);
            #pragma unroll
            for (int i = 0; i < 2; ++i) {
                int s = i * 512 + t;
                int col = s >> 2;
                int kcd2 = (s & 3) ^ ((col >> 2) & 3);
                async_load16(w4t + (size_t)col * 1024 + ke + kcd2 * 8,
                             Bsm + i * 8192 + w * 1024);
            }
        };
        f32x4 acc[4][4] = {};
        stageA(0, 0); stageA(32, 1);
        for (int k0i = 0; k0i < 32; ++k0i) {
            if (k0i + 1 < 32)
                asm volatile("s_waitcnt vmcnt(3)\n\ts_barrier" ::: "memory");
            else
                asm volatile("s_waitcnt vmcnt(0)\n\ts_barrier" ::: "memory");
            if (k0i + 2 < 32) stageA((k0i + 2) * 32, (k0i + 2) % 3);
            const bf16* As16 = (const bf16*)(smem + (k0i % 3) * STAGE);
            const bf16* Bs16 = (const bf16*)(smem + (k0i % 3) * STAGE + ASZ);
            bf16x8 af[4], bfr[4];
            #pragma unroll
            for (int r = 0; r < 4; ++r) {
                int row = rg * 64 + r * 16 + mi;
                int slot = row * 4 + (q ^ ((row >> 2) & 3));
                af[r] = *(const bf16x8*)(As16 + slot * 8);
            }
            #pragma unroll
            for (int c = 0; c < 4; ++c) {
                int col = cgr * 64 + c * 16 + mi;
                int slot = col * 4 + (q ^ ((col >> 2) & 3));
                bfr[c] = *(const bf16x8*)(Bs16 + slot * 8);
            }
            #pragma unroll
            for (int r = 0; r < 4; ++r)
                #pragma unroll
                for (int c = 0; c < 4; ++c)
                    acc[r][c] = __builtin_amdgcn_mfma_f32_16x16x32_bf16(af[r], bfr[c], acc[r][c], 0, 0, 0);
        }
        #pragma unroll
        for (int r = 0; r < 4; ++r) {
            int rowb = rg * 64 + r * 16 + q * 4;
            #pragma unroll
            for (int c = 0; c < 4; ++c) {
                int col = cgr * 64 + c * 16 + mi;
                float bv = b4[col];
                int chunk = col >> 3;
                #pragma unroll
                for (int i = 0; i < 4; ++i) {
                    int row = rowb + i;
                    Ht[(row * 32 + (chunk ^ (row & 31))) * 8 + (col & 7)] =
                        __float2bfloat16(acc[r][c][i] + bv);
                }
            }
        }
    }
    __syncthreads();

    const int c0w = w * 32;     // wave's 32-col slice for phases B/C/D
    const bf16* Bg0 = w4t + (size_t)(c0w + mi) * 1024 + q * 8;
    const bf16* Bg1 = w4t + (size_t)(c0w + 16 + mi) * 1024 + q * 8;

    // ---- phase B: 32 rows -> Ht2 (barrier-free; B direct-to-reg) ----
    {
        f32x4 acc[2][2] = {};
        #pragma unroll 4
        for (int ks = 0; ks < 32; ++ks) {
            bf16x8 b0 = *(const bf16x8*)(Bg0 + ks * 32);
            bf16x8 b1 = *(const bf16x8*)(Bg1 + ks * 32);
            int kc = (ks & 7) * 4 + q;
            int r2a = 4 * mi + (ks >> 3);
            int r2b = 4 * (16 + mi) + (ks >> 3);
            bf16x8 a0 = *(const bf16x8*)(Ht + (r2a * 32 + (kc ^ (r2a & 31))) * 8);
            bf16x8 a1 = *(const bf16x8*)(Ht + (r2b * 32 + (kc ^ (r2b & 31))) * 8);
            acc[0][0] = __builtin_amdgcn_mfma_f32_16x16x32_bf16(a0, b0, acc[0][0], 0, 0, 0);
            acc[0][1] = __builtin_amdgcn_mfma_f32_16x16x32_bf16(a0, b1, acc[0][1], 0, 0, 0);
            acc[1][0] = __builtin_amdgcn_mfma_f32_16x16x32_bf16(a1, b0, acc[1][0], 0, 0, 0);
            acc[1][1] = __builtin_amdgcn_mfma_f32_16x16x32_bf16(a1, b1, acc[1][1], 0, 0, 0);
        }
        #pragma unroll
        for (int f = 0; f < 2; ++f) {
            #pragma unroll
            for (int g = 0; g < 2; ++g) {
                int col = c0w + g * 16 + mi;
                float bv = b4[col];
                int chunk = col >> 3;
                #pragma unroll
                for (int i = 0; i < 4; ++i) {
                    int row = f * 16 + q * 4 + i;
                    Ht2[(row * 32 + (chunk ^ (row & 31))) * 8 + (col & 7)] =
                        __float2bfloat16(acc[f][g][i] + bv);
                }
            }
        }
    }
    __syncthreads();

    // ---- phase C: 8 rows -> Ht3 (barrier-free; B direct-to-reg) ----
    {
        f32x4 acc[2] = {};
        #pragma unroll 4
        for (int ks = 0; ks < 32; ++ks) {
            bf16x8 b0 = *(const bf16x8*)(Bg0 + ks * 32);
            bf16x8 b1 = *(const bf16x8*)(Bg1 + ks * 32);
            int kc = (ks & 7) * 4 + q;
            int r3 = (4 * mi + (ks >> 3)) & 31;
            bf16x8 a = *(const bf16x8*)(Ht2 + (r3 * 32 + (kc ^ (r3 & 31))) * 8);
            acc[0] = __builtin_amdgcn_mfma_f32_16x16x32_bf16(a, b0, acc[0], 0, 0, 0);
            acc[1] = __builtin_amdgcn_mfma_f32_16x16x32_bf16(a, b1, acc[1], 0, 0, 0);
        }
        if (q < 2) {
            #pragma unroll
            for (int g = 0; g < 2; ++g) {
                int col = c0w + g * 16 + mi;
                float bv = b4[col];
                #pragma unroll
                for (int i = 0; i < 4; ++i)
                    Ht3[(q * 4 + i) * 256 + col] = __float2bfloat16(acc[g][i] + bv);
            }
        }
    }
    __syncthreads();

    // ---- phase D: 2 roots -> out (barrier-free; B direct-to-reg) ----
    {
        f32x4 acc[2] = {};
        #pragma unroll 4
        for (int ks = 0; ks < 32; ++ks) {
            bf16x8 b0 = *(const bf16x8*)(Bg0 + ks * 32);
            bf16x8 b1 = *(const bf16x8*)(Bg1 + ks * 32);
            int r4 = (4 * (mi & 1) + (ks >> 3)) & 7;
            bf16x8 a = *(const bf16x8*)(Ht3 + r4 * 256 + (ks & 7) * 32 + q * 8);
            acc[0] = __builtin_amdgcn_mfma_f32_16x16x32_bf16(a, b0, acc[0], 0, 0, 0);
            acc[1] = __builtin_amdgcn_mfma_f32_16x16x32_bf16(a, b1, acc[1], 0, 0, 0);
        }
        if (q == 0) {
            #pragma unroll
            for (int g = 0; g < 2; ++g) {
                int col = c0w + g * 16 + mi;
                float bv = b4[col];
                #pragma unroll
                for (int i = 0; i < 2; ++i)
                    out[(size_t)(b * 2 + i) * 256 + col] = acc[g][i] + bv;
            }
        }
    }
}

extern "C" void kernel_launch(void* const* d_in, const int* in_sizes, int n_in,
                              void* d_out, int out_size, void* d_ws, size_t ws_size,
                              hipStream_t stream) {
    const int*   ids = (const int*)d_in[0];
    const float* emb = (const float*)d_in[1];
    const float* W1  = (const float*)d_in[2];
    const float* b1  = (const float*)d_in[3];
    const float* W2  = (const float*)d_in[4];
    const float* b2  = (const float*)d_in[5];
    (void)in_sizes; (void)n_in; (void)out_size; (void)ws_size;

    char* ws = (char*)d_ws;
    size_t off = 0;
    float* zbuf = (float*)(ws + off); off += 1024;
    float* b4   = (float*)(ws + off); off += 1024;
    bf16* w1t = (bf16*)(ws + off); off += (size_t)256 * KP1 * 2;     // 160 KB
    bf16* w2t = (bf16*)(ws + off); off += (size_t)256 * 512 * 2;     // 256 KB
    bf16* w2b = (bf16*)(ws + off); off += (size_t)512 * 256 * 2;     // 256 KB
    bf16* w4t = (bf16*)(ws + off); off += (size_t)256 * 1024 * 2;    // 512 KB
    bf16* proj = (bf16*)(ws + off); off += (size_t)MP * 256 * 2;     // 25.8 MB
    bf16* h  = (bf16*)(ws + off); off += (size_t)65536 * 256 * 2;    // 33.5 MB
    (void)off;

    // D1: weight casts/transposes + b4 + zeros
    prep_w<<<1345, 256, 0, stream>>>(W1, W2, b2, w1t, w2t, w2b, b4, zbuf);

    // D2: W4T (blocks 0..7) || proj (blocks 8..401, 2-stage PIPE raw barriers)
    combo<<<402, 512, 0, stream>>>(emb, w1t, b1, w2t, w2b, w4t, proj, zbuf);

    // D3: main — leaves + levels 0-1 fused (PIPE)
    mainK<<<512, 512, 0, stream>>>(proj, ids, w4t, b4, h);

    // D4: levels 2-9 block-local: t1 tile (PIPE) + B/C/D direct-B barrier-free
    treeK<<<128, 512, 0, stream>>>(h, w4t, b4, (float*)d_out);
}

// Round 6
// 200.101 us; speedup vs baseline: 1.2637x; 1.1864x over previous
//
#include <hip/hip_runtime.h>
#include <hip/hip_bf16.h>
#include <stdint.h>

#define VOCAB 50257
#define WD 300
#define KP1 320              // word dim padded to mult of 32
#define MP 50432             // vocab rows padded: 394*128

using bf16 = __hip_bfloat16;
typedef __attribute__((ext_vector_type(4))) float f32x4;
typedef __attribute__((ext_vector_type(8))) short bf16x8;

// async global->LDS, 16B per lane; LDS dest = wave-uniform base + lane*16
__device__ __forceinline__ void async_load16(const void* g, void* l) {
    __builtin_amdgcn_global_load_lds(
        (const __attribute__((address_space(1))) uint32_t*)(uintptr_t)g,
        (__attribute__((address_space(3))) uint32_t*)l, 16, 0, 0);
}

// ---------- prep: w1t = W1^T bf16 [256x320]; w2t = W2^T bf16 [256x512];
//                  w2b = W2 cast bf16 [512x256]; b4 = b2@(A+B)+b2; zbuf zeros
__global__ void prep_w(const float* __restrict__ W1, const float* __restrict__ W2,
                       const float* __restrict__ b2,
                       bf16* __restrict__ w1t, bf16* __restrict__ w2t,
                       bf16* __restrict__ w2b, float* __restrict__ b4,
                       float* __restrict__ zbuf) {
    if (blockIdx.x == 1344) {           // bias block: b4 = b2@(A+B) + b2
        __shared__ float b2s[256];
        int n = threadIdx.x;
        b2s[n] = b2[n];
        zbuf[n] = 0.0f;
        __syncthreads();
        float acc = b2s[n];
        #pragma unroll 8
        for (int k = 0; k < 256; ++k)
            acc += b2s[k] * (W2[k * 256 + n] + W2[(k + 256) * 256 + n]);
        b4[n] = acc;
        return;
    }
    int idx = blockIdx.x * 256 + threadIdx.x;
    if (idx < 256 * KP1) {                              // w1t = W1^T (zero-pad)
        int n = idx / KP1;
        int k = idx - n * KP1;
        w1t[idx] = __float2bfloat16(k < WD ? W1[k * 256 + n] : 0.0f);
    } else if (idx < 256 * KP1 + 131072) {              // w2t = W2^T
        int j = idx - 256 * KP1;
        int n = j >> 9, k = j & 511;
        w2t[j] = __float2bfloat16(W2[k * 256 + n]);
    } else {                                            // w2b = cast(W2)
        int j = idx - 256 * KP1 - 131072;
        w2b[j] = __float2bfloat16(W2[j]);
    }
}

// ---------- unified 128-row x 256-col tile (8 waves: 2 rg x 4 cgr) -----------
// AMODE 0: A bf16, row stride As elems; 3-stage PIPE (verified R8/R10/R12)
// AMODE 1: A row r = concat4(proj[ids4[m0+r]]), K = 1024; 3-stage PIPE
// AMODE 2: A fp32 rows stride WD (emb, clamped); 2-stage PIPE w/ raw barriers
template <int AMODE, bool OUT_F32>
__device__ __forceinline__ void tile_gemm(
    char* smem, const void* Av, const int* ids,
    const bf16* BT, int Bstr, const float* bias,
    void* C, int Cs, int coff, int K, int As, int m0,
    const float* zbuf)
{
    constexpr int ASZ = (AMODE == 2) ? 16384 : 8192;
    constexpr int BSZ = 16384, STAGE = ASZ + BSZ;

    const int t = threadIdx.x, w = t >> 6, lane = t & 63;
    const int rg = w >> 2, cgr = w & 3, mi = lane & 15, q = lane >> 4;
    const bf16* Ab = (const bf16*)Av;

    int4 idq = {0, 0, 0, 0};
    if constexpr (AMODE == 1) idq = ((const int4*)ids)[m0 + (t >> 2)];

    auto stage = [&](int ke, int buf) {
        char* Asm = smem + buf * STAGE;
        char* Bsm = Asm + ASZ;
        if constexpr (AMODE == 2) {
            const float* A32 = (const float*)Av;
            #pragma unroll
            for (int i = 0; i < 2; ++i) {
                int s = i * 512 + t;
                int row = s >> 3;
                int kcd = (s & 7) ^ (row & 7);
                int k = ke + kcd * 4;
                int grow = m0 + row; if (grow >= VOCAB) grow = VOCAB - 1;
                const float* g = (k <= 296) ? (A32 + (size_t)grow * WD + k) : zbuf;
                async_load16(g, Asm + i * 8192 + w * 1024);
            }
        } else {
            int row = t >> 2;
            int kcd = (t & 3) ^ ((row >> 2) & 3);
            const bf16* g;
            if constexpr (AMODE == 1) {
                int sel = ke >> 8;
                int id = (sel & 2) ? ((sel & 1) ? idq.w : idq.z)
                                   : ((sel & 1) ? idq.y : idq.x);
                g = Ab + (size_t)id * 256 + (ke & 255) + kcd * 8;
            } else {
                g = Ab + (size_t)(m0 + row) * As + ke + kcd * 8;
            }
            async_load16(g, Asm + w * 1024);
        }
        #pragma unroll
        for (int i = 0; i < 2; ++i) {
            int s = i * 512 + t;
            int col = s >> 2;
            int kcd = (s & 3) ^ ((col >> 2) & 3);
            async_load16(BT + (size_t)col * Bstr + ke + kcd * 8,
                         Bsm + i * 8192 + w * 1024);
        }
    };

    f32x4 acc[4][4] = {};

    auto compute = [&](int buf) {
        const char* Asm = smem + buf * STAGE;
        const bf16* Bs16 = (const bf16*)(Asm + ASZ);
        bf16x8 af[4], bfr[4];
        if constexpr (AMODE == 2) {
            const float* As32 = (const float*)Asm;
            #pragma unroll
            for (int r = 0; r < 4; ++r) {
                int row = rg * 64 + r * 16 + mi;
                int sl = row * 8 + ((2 * q) ^ (row & 7));
                f32x4 lo = *(const f32x4*)(As32 + sl * 4);
                f32x4 hi = *(const f32x4*)(As32 + (sl ^ 1) * 4);
                union { bf16x8 v; bf16 hh[8]; } u;
                #pragma unroll
                for (int j = 0; j < 4; ++j) u.hh[j] = __float2bfloat16(lo[j]);
                #pragma unroll
                for (int j = 0; j < 4; ++j) u.hh[4 + j] = __float2bfloat16(hi[j]);
                af[r] = u.v;
            }
        } else {
            const bf16* As16 = (const bf16*)Asm;
            #pragma unroll
            for (int r = 0; r < 4; ++r) {
                int row = rg * 64 + r * 16 + mi;
                int slot = row * 4 + (q ^ ((row >> 2) & 3));
                af[r] = *(const bf16x8*)(As16 + slot * 8);
            }
        }
        #pragma unroll
        for (int c = 0; c < 4; ++c) {
            int col = cgr * 64 + c * 16 + mi;
            int slot = col * 4 + (q ^ ((col >> 2) & 3));
            bfr[c] = *(const bf16x8*)(Bs16 + slot * 8);
        }
        #pragma unroll
        for (int r = 0; r < 4; ++r)
            #pragma unroll
            for (int c = 0; c < 4; ++c)
                acc[r][c] = __builtin_amdgcn_mfma_f32_16x16x32_bf16(af[r], bfr[c], acc[r][c], 0, 0, 0);
    };

    const int S = K >> 5;
    if constexpr (AMODE == 2) {
        // 2-stage PIPE with raw barriers (no compiler vmcnt(0) drain)
        stage(0, 0);
        for (int k0 = 0; k0 < S; ++k0) {
            if (k0 + 1 < S) {
                stage((k0 + 1) * 32, (k0 + 1) & 1);
                asm volatile("s_waitcnt vmcnt(4)\n\ts_barrier" ::: "memory");
            } else {
                asm volatile("s_waitcnt vmcnt(0)\n\ts_barrier" ::: "memory");
            }
            compute(k0 & 1);
            asm volatile("s_waitcnt lgkmcnt(0)\n\ts_barrier" ::: "memory");
        }
    } else {
        stage(0, 0);
        if (S > 1) stage(32, 1);
        for (int k0 = 0; k0 < S; ++k0) {
            if (k0 + 1 < S)
                asm volatile("s_waitcnt vmcnt(3)\n\ts_barrier" ::: "memory");
            else
                asm volatile("s_waitcnt vmcnt(0)\n\ts_barrier" ::: "memory");
            if (k0 + 2 < S) stage((k0 + 2) * 32, (k0 + 2) % 3);
            compute(k0 % 3);
        }
    }

    // epilogue: C/D layout col = lane&15, row = (lane>>4)*4 + i
    #pragma unroll
    for (int r = 0; r < 4; ++r) {
        int rowb = m0 + rg * 64 + r * 16 + q * 4;
        #pragma unroll
        for (int c = 0; c < 4; ++c) {
            int col = cgr * 64 + c * 16 + mi;
            float bv = bias[col];
            #pragma unroll
            for (int i = 0; i < 4; ++i) {
                float v = acc[r][c][i] + bv;
                size_t o = (size_t)(rowb + i) * Cs + coff + col;
                if (OUT_F32) ((float*)C)[o] = v;
                else         ((bf16*)C)[o] = __float2bfloat16(v);
            }
        }
    }
}

// ---------- D2: W4T (blocks 0..7) || proj (blocks 8..401) --------------------
__global__ __launch_bounds__(512)
void combo(const float* __restrict__ emb, const bf16* __restrict__ w1t,
           const float* __restrict__ b1, const bf16* __restrict__ w2t,
           const bf16* __restrict__ w2b, bf16* __restrict__ w4t,
           bf16* __restrict__ proj, const float* __restrict__ zbuf) {
    __shared__ char smem[73728];
    int blk = blockIdx.x;
    if (blk < 8) {
        int j = blk >> 1, s = blk & 1;
        tile_gemm<0, false>(smem, w2t + 256 * (j >> 1), nullptr,
                            w2b + 65536 * (j & 1), 256, zbuf,
                            w4t, 1024, 256 * j, 256, 512, s * 128, nullptr);
    } else {
        tile_gemm<2, false>(smem, emb, nullptr, w1t, KP1, b1,
                            proj, 256, 0, KP1, WD, (blk - 8) * 128, zbuf);
    }
}

// ---------- D3: main — h = concat4(proj[ids4]) @ W4 + b4 ---------------------
// blocks 512..519: build w4c (coalesced-B permutation of w4t):
//   unit u (16B) = (cg*32+ks)*64 + lane; holds w4t[cg*16+mi][ks*32+q*8 .. +7]
//   (lane = q*16+mi) -> one wave's B-frag for (cg,ks) is contiguous 1 KB.
__global__ __launch_bounds__(512)
void mainK(const bf16* __restrict__ proj, const int* __restrict__ ids,
           const bf16* __restrict__ w4t, bf16* __restrict__ w4c,
           const float* __restrict__ b4, bf16* __restrict__ h) {
    __shared__ char smem[73728];
    if (blockIdx.x >= 512) {
        const int tid = (blockIdx.x - 512) * 512 + threadIdx.x;  // 4096 threads
        #pragma unroll
        for (int i = 0; i < 8; ++i) {
            int u = i * 4096 + tid;                // 32768 units total
            int ln = u & 63, ks = (u >> 6) & 31, cg = u >> 11;
            int mi2 = ln & 15, q2 = ln >> 4;
            *(int4*)(w4c + (size_t)u * 8) =
                *(const int4*)(w4t + (size_t)(cg * 16 + mi2) * 1024 + ks * 32 + q2 * 8);
        }
        return;
    }
    tile_gemm<1, false>(smem, proj, ids, w4t, 1024, b4,
                        h, 256, 0, 1024, 256, blockIdx.x * 128, nullptr);
}

// ---------- D4: treeK — levels 2-10 block-local (256 blocks, all CUs) --------
// Block b: phase A: t1 rows 64b..64b+63 (64x256, K=1024, 16 fat rounds of 64k,
//   R1-verified 2-stage raw-barrier pipe, uniform 5 loads/thread/stage).
// Phases B/C/D: 16/4/1 out rows, A from LDS (Ht/Ht2/Ht3), B streamed
//   global->VGPR from w4c COALESCED (1KB/wave/frag). 3 __syncthreads total.
__global__ __launch_bounds__(512)
void treeK(const bf16* __restrict__ h, const bf16* __restrict__ w4t,
           const bf16* __restrict__ w4c, const float* __restrict__ b4,
           float* __restrict__ out) {
    constexpr int ASZ = 8192, BSZ = 32768, STAGE = ASZ + BSZ;
    __shared__ char smem[2 * STAGE];   // 80 KB pipe
    __shared__ bf16 Ht[64 * 256];      // 32 KB
    __shared__ bf16 Ht2[16 * 256];     // 8 KB
    __shared__ bf16 Ht3[4 * 256];      // 2 KB  (total 122 KB)

    const int t = threadIdx.x, w = t >> 6, lane = t & 63;
    const int mi = lane & 15, q = lane >> 4;
    const int b = blockIdx.x;

    // ---- phase A: 64x256 tile, K=1024, 16 rounds x 64k -> Ht ----
    {
        auto stage = [&](int r, int buf) {
            char* As = smem + buf * STAGE;
            char* Bs = As + ASZ;
            const int kb = r * 64;
            {   // A: 64 rows x 64k; row=t>>3, chunk c=t&7 stored at c^(row&7)
                int row = t >> 3, c = t & 7;
                async_load16(h + (size_t)(64 * b + row) * 1024 + kb + ((c ^ (row & 7)) << 3),
                             As + w * 1024);
            }
            #pragma unroll
            for (int sub = 0; sub < 2; ++sub)       // B: 256 cols x 64k (R1 stageF)
                #pragma unroll
                for (int i = 0; i < 2; ++i) {
                    int s = i * 512 + t;
                    int col = s >> 2;
                    int kcd = (s & 3) ^ ((col >> 2) & 3);
                    async_load16(w4t + (size_t)col * 1024 + kb + sub * 32 + kcd * 8,
                                 Bs + sub * 16384 + i * 8192 + w * 1024);
                }
        };
        f32x4 acc[4][2] = {};
        stage(0, 0);
        for (int r = 0; r < 16; ++r) {
            if (r + 1 < 16) {
                stage(r + 1, (r + 1) & 1);
                asm volatile("s_waitcnt vmcnt(5)\n\ts_barrier" ::: "memory");
            } else {
                asm volatile("s_waitcnt vmcnt(0)\n\ts_barrier" ::: "memory");
            }
            const bf16* As16 = (const bf16*)(smem + (r & 1) * STAGE);
            const bf16* Bb   = (const bf16*)(smem + (r & 1) * STAGE + ASZ);
            #pragma unroll
            for (int kk = 0; kk < 2; ++kk) {
                bf16x8 af[4], bfr[2];
                #pragma unroll
                for (int ri = 0; ri < 4; ++ri) {
                    int row = ri * 16 + mi;
                    int c = kk * 4 + q;
                    af[ri] = *(const bf16x8*)(As16 + (row * 8 + (c ^ (row & 7))) * 8);
                }
                #pragma unroll
                for (int c4 = 0; c4 < 2; ++c4) {
                    int col = w * 32 + c4 * 16 + mi;
                    int slot = col * 4 + (q ^ ((col >> 2) & 3));
                    bfr[c4] = *(const bf16x8*)(Bb + kk * 8192 + slot * 8);
                }
                #pragma unroll
                for (int ri = 0; ri < 4; ++ri)
                    #pragma unroll
                    for (int c4 = 0; c4 < 2; ++c4)
                        acc[ri][c4] = __builtin_amdgcn_mfma_f32_16x16x32_bf16(af[ri], bfr[c4], acc[ri][c4], 0, 0, 0);
            }
            asm volatile("s_waitcnt lgkmcnt(0)\n\ts_barrier" ::: "memory");
        }
        // epilogue -> Ht (XOR-swizzled, matches phase-B read formula)
        #pragma unroll
        for (int ri = 0; ri < 4; ++ri) {
            #pragma unroll
            for (int c4 = 0; c4 < 2; ++c4) {
                int col = w * 32 + c4 * 16 + mi;
                float bv = b4[col];
                int chunk = col >> 3;
                #pragma unroll
                for (int i = 0; i < 4; ++i) {
                    int row = ri * 16 + q * 4 + i;
                    Ht[(row * 32 + (chunk ^ (row & 31))) * 8 + (col & 7)] =
                        __float2bfloat16(acc[ri][c4][i] + bv);
                }
            }
        }
    }
    __syncthreads();

    // ---- phase B: 16 rows -> Ht2 (B coalesced from w4c) ----
    {
        f32x4 acc[2] = {};
        #pragma unroll 8
        for (int ks = 0; ks < 32; ++ks) {
            int kc = (ks & 7) * 4 + q;
            int r2 = 4 * mi + (ks >> 3);
            bf16x8 a = *(const bf16x8*)(Ht + (r2 * 32 + (kc ^ (r2 & 31))) * 8);
            #pragma unroll
            for (int g = 0; g < 2; ++g) {
                bf16x8 bb = *(const bf16x8*)(w4c + ((size_t)((2 * w + g) * 32 + ks) * 64 + lane) * 8);
                acc[g] = __builtin_amdgcn_mfma_f32_16x16x32_bf16(a, bb, acc[g], 0, 0, 0);
            }
        }
        #pragma unroll
        for (int g = 0; g < 2; ++g) {
            int col = w * 32 + g * 16 + mi;
            float bv = b4[col];
            int chunk = col >> 3;
            #pragma unroll
            for (int i = 0; i < 4; ++i) {
                int row = q * 4 + i;
                Ht2[(row * 32 + (chunk ^ (row & 15))) * 8 + (col & 7)] =
                    __float2bfloat16(acc[g][i] + bv);
            }
        }
    }
    __syncthreads();

    // ---- phase C: 4 rows -> Ht3 (B coalesced from w4c) ----
    {
        f32x4 acc[2] = {};
        #pragma unroll 8
        for (int ks = 0; ks < 32; ++ks) {
            int kc = (ks & 7) * 4 + q;
            int r3 = (4 * mi + (ks >> 3)) & 15;
            bf16x8 a = *(const bf16x8*)(Ht2 + (r3 * 32 + (kc ^ (r3 & 15))) * 8);
            #pragma unroll
            for (int g = 0; g < 2; ++g) {
                bf16x8 bb = *(const bf16x8*)(w4c + ((size_t)((2 * w + g) * 32 + ks) * 64 + lane) * 8);
                acc[g] = __builtin_amdgcn_mfma_f32_16x16x32_bf16(a, bb, acc[g], 0, 0, 0);
            }
        }
        if (q == 0) {
            #pragma unroll
            for (int g = 0; g < 2; ++g) {
                int col = w * 32 + g * 16 + mi;
                float bv = b4[col];
                #pragma unroll
                for (int i = 0; i < 4; ++i)
                    Ht3[i * 256 + col] = __float2bfloat16(acc[g][i] + bv);
            }
        }
    }
    __syncthreads();

    // ---- phase D: 1 root -> out (B coalesced from w4c) ----
    {
        f32x4 acc[2] = {};
        #pragma unroll 8
        for (int ks = 0; ks < 32; ++ks) {
            int r4 = (4 * mi + (ks >> 3)) & 3;
            bf16x8 a = *(const bf16x8*)(Ht3 + r4 * 256 + (ks & 7) * 32 + q * 8);
            #pragma unroll
            for (int g = 0; g < 2; ++g) {
                bf16x8 bb = *(const bf16x8*)(w4c + ((size_t)((2 * w + g) * 32 + ks) * 64 + lane) * 8);
                acc[g] = __builtin_amdgcn_mfma_f32_16x16x32_bf16(a, bb, acc[g], 0, 0, 0);
            }
        }
        if (q == 0) {
            #pragma unroll
            for (int g = 0; g < 2; ++g) {
                int col = w * 32 + g * 16 + mi;
                out[(size_t)b * 256 + col] = acc[g][0] + b4[col];
            }
        }
    }
}

extern "C" void kernel_launch(void* const* d_in, const int* in_sizes, int n_in,
                              void* d_out, int out_size, void* d_ws, size_t ws_size,
                              hipStream_t stream) {
    const int*   ids = (const int*)d_in[0];
    const float* emb = (const float*)d_in[1];
    const float* W1  = (const float*)d_in[2];
    const float* b1  = (const float*)d_in[3];
    const float* W2  = (const float*)d_in[4];
    const float* b2  = (const float*)d_in[5];
    (void)in_sizes; (void)n_in; (void)out_size; (void)ws_size;

    char* ws = (char*)d_ws;
    size_t off = 0;
    float* zbuf = (float*)(ws + off); off += 1024;
    float* b4   = (float*)(ws + off); off += 1024;
    bf16* w1t = (bf16*)(ws + off); off += (size_t)256 * KP1 * 2;     // 160 KB
    bf16* w2t = (bf16*)(ws + off); off += (size_t)256 * 512 * 2;     // 256 KB
    bf16* w2b = (bf16*)(ws + off); off += (size_t)512 * 256 * 2;     // 256 KB
    bf16* w4t = (bf16*)(ws + off); off += (size_t)256 * 1024 * 2;    // 512 KB
    bf16* w4c = (bf16*)(ws + off); off += (size_t)256 * 1024 * 2;    // 512 KB
    bf16* proj = (bf16*)(ws + off); off += (size_t)MP * 256 * 2;     // 25.8 MB
    bf16* h  = (bf16*)(ws + off); off += (size_t)65536 * 256 * 2;    // 33.5 MB
    (void)off;

    // D1: weight casts/transposes + b4 + zeros
    prep_w<<<1345, 256, 0, stream>>>(W1, W2, b2, w1t, w2t, w2b, b4, zbuf);

    // D2: W4T (blocks 0..7) || proj (blocks 8..401, 2-stage PIPE raw barriers)
    combo<<<402, 512, 0, stream>>>(emb, w1t, b1, w2t, w2b, w4t, proj, zbuf);

    // D3: main — leaves + levels 0-1 fused (PIPE); blocks 512..519 build w4c
    mainK<<<520, 512, 0, stream>>>(proj, ids, w4t, w4c, b4, h);

    // D4: levels 2-10 block-local, 256 blocks (all CUs)
    treeK<<<256, 512, 0, stream>>>(h, w4t, w4c, b4, (float*)d_out);
}